// Round 2
// baseline (171.558 us; speedup 1.0000x reference)
//
#include <hip/hip_runtime.h>
#include <math.h>

#define BB 2
#define NN 1024
#define DD 48
#define DH 12
#define BI 16
#define BJ 16
#define PSTR 49   // padded pos-tile row stride

__device__ __forceinline__ float gelu_exact(float x) {
    return 0.5f * x * (1.0f + erff(x * 0.70710678118654752f));
}
__device__ __forceinline__ float softplus_f(float x) {
    return (x > 20.0f) ? x : log1pf(expf(x));
}

// ---------------- mass MLP + force accumulator zeroing ----------------
__global__ void mass_kernel(const float* __restrict__ pos,
                            const float* __restrict__ m_w1, const float* __restrict__ m_b1,
                            const float* __restrict__ m_w2, const float* __restrict__ m_b2,
                            float* __restrict__ mass_out, float* __restrict__ force_acc) {
    int p = blockIdx.x * blockDim.x + threadIdx.x;
    if (p >= BB * NN) return;

    // zero this particle's force row (replay-safe: no memset needed)
    float* fr = force_acc + (size_t)p * DD;
    #pragma unroll
    for (int d = 0; d < DD; ++d) fr[d] = 0.0f;

    const float* pp = pos + p * DD;
    float x[DD];
    #pragma unroll
    for (int d = 0; d < DD; ++d) x[d] = pp[d];
    float m2 = m_b2[0];
    #pragma unroll
    for (int k = 0; k < DH; ++k) {
        float h = m_b1[k];
        #pragma unroll
        for (int d = 0; d < DD; ++d) h += x[d] * m_w1[d * DH + k];
        m2 += gelu_exact(h) * m_w2[k];
    }
    mass_out[p] = softplus_f(m2);
}

// ---------------- pairwise force ----------------
__global__ __launch_bounds__(256) void force_kernel(
    const float* __restrict__ pos,
    const float* __restrict__ f_w1, const float* __restrict__ f_b1,
    const float* __restrict__ f_w2, const float* __restrict__ f_b2,
    const float* __restrict__ f_w3, const float* __restrict__ f_b3,
    const float* __restrict__ mass, float* __restrict__ force_acc) {
    __shared__ float sPi[BI * PSTR];
    __shared__ float sPj[BJ * PSTR];
    __shared__ float sW2T[DD * DD];   // sW2T[k*48+c] = w2[c][k]
    __shared__ float sW1[3 * DD];
    __shared__ float sB1[DD];
    __shared__ float sB2[DD];
    __shared__ float sW3[DD];
    __shared__ float sMi[BI], sMj[BJ];
    __shared__ float sRat[BI][BJ + 1];

    const int tpb = NN / BI;              // 64
    const int TP = tpb * (tpb + 1) / 2;   // 2080
    int bid = blockIdx.x;
    int b = bid / TP;
    int tp = bid - b * TP;
    int it = (int)((sqrtf(8.0f * (float)tp + 1.0f) - 1.0f) * 0.5f);
    while ((it + 1) * (it + 2) / 2 <= tp) ++it;
    while (it * (it + 1) / 2 > tp) --it;
    int jt = tp - it * (it + 1) / 2;

    int i0 = it * BI, j0 = jt * BJ;
    int tid = threadIdx.x;

    for (int e = tid; e < DD * DD; e += 256) {
        int c = e / DD, k = e - c * DD;
        sW2T[k * DD + c] = f_w2[e];
    }
    if (tid < 3 * DD) sW1[tid] = f_w1[tid];
    if (tid < DD) { sB1[tid] = f_b1[tid]; sB2[tid] = f_b2[tid]; sW3[tid] = f_w3[tid]; }
    for (int e = tid; e < BI * DD; e += 256) {
        int r = e / DD, d = e - r * DD;
        sPi[r * PSTR + d] = pos[(b * NN + i0 + r) * DD + d];
        sPj[r * PSTR + d] = pos[(b * NN + j0 + r) * DD + d];
    }
    if (tid < BI) sMi[tid] = mass[b * NN + i0 + tid];
    else if (tid < BI + BJ) sMj[tid - BI] = mass[b * NN + j0 + (tid - BI)];
    __syncthreads();

    // ---- Phase A: one thread per (i,j) pair ----
    int ti = tid >> 4, tj = tid & 15;
    int gi = i0 + ti, gj = j0 + tj;
    const float* pi = &sPi[ti * PSTR];
    const float* pj = &sPj[tj * PSTR];

    float s2 = 0.0f;
    #pragma unroll
    for (int d = 0; d < DD; ++d) { float df = pi[d] - pj[d]; s2 += df * df; }
    float dist = fmaxf(sqrtf(s2), 0.01f);

    float mi = sMi[ti], mj = sMj[tj];
    float h1[DD];
    #pragma unroll 4
    for (int k = 0; k < DD; ++k) {
        float t = sB1[k] + dist * sW1[k] + mi * sW1[DD + k] + mj * sW1[2 * DD + k];
        h1[k] = gelu_exact(t);
    }
    float fm = f_b3[0];
    #pragma unroll 4
    for (int k = 0; k < DD; ++k) {
        float t = sB2[k];
        const float* wr = &sW2T[k * DD];
        #pragma unroll
        for (int c = 0; c < DD; ++c) t += h1[c] * wr[c];
        fm += gelu_exact(t) * sW3[k];
    }
    float ratio = (gj <= gi) ? (fm / dist) : 0.0f;  // j==i: disp=0 -> contributes 0
    sRat[ti][tj] = ratio;
    __syncthreads();

    // ---- Phase B: thread=(i, d-group of 3) accumulates over j ----
    int ti2 = tid >> 4, dg = tid & 15;
    int d0 = dg * 3;
    const float* pi2 = &sPi[ti2 * PSTR];
    float f0 = 0.0f, f1 = 0.0f, f2 = 0.0f;
    #pragma unroll
    for (int t = 0; t < BJ; ++t) {
        float r = sRat[ti2][t];
        const float* pj2 = &sPj[t * PSTR];
        f0 += r * (pi2[d0 + 0] - pj2[d0 + 0]);
        f1 += r * (pi2[d0 + 1] - pj2[d0 + 1]);
        f2 += r * (pi2[d0 + 2] - pj2[d0 + 2]);
    }
    float* fdst = force_acc + ((size_t)(b * NN + i0 + ti2) * DD + d0);
    atomicAdd(fdst + 0, f0);
    atomicAdd(fdst + 1, f1);
    atomicAdd(fdst + 2, f2);
}

// ---------------- integrate ----------------
__global__ void integrate_kernel(const float* __restrict__ pos, const float* __restrict__ vel,
                                 const float* __restrict__ force, const float* __restrict__ mass,
                                 const float* __restrict__ damping_p, const float* __restrict__ dt_p,
                                 float* __restrict__ out) {
    int e = blockIdx.x * blockDim.x + threadIdx.x;
    if (e >= BB * NN * DD) return;
    int p = e / DD;
    float damping = damping_p[0], dt = dt_p[0];
    float acc = force[e] / (mass[p] + 0.1f);
    float nv = damping * vel[e] + dt * acc;
    float np = pos[e] + dt * nv;
    out[e] = np;
    out[BB * NN * DD + e] = nv;
}

extern "C" void kernel_launch(void* const* d_in, const int* in_sizes, int n_in,
                              void* d_out, int out_size, void* d_ws, size_t ws_size,
                              hipStream_t stream) {
    const float* pos  = (const float*)d_in[0];
    const float* vel  = (const float*)d_in[1];
    const float* m_w1 = (const float*)d_in[2];
    const float* m_b1 = (const float*)d_in[3];
    const float* m_w2 = (const float*)d_in[4];
    const float* m_b2 = (const float*)d_in[5];
    const float* f_w1 = (const float*)d_in[6];
    const float* f_b1 = (const float*)d_in[7];
    const float* f_w2 = (const float*)d_in[8];
    const float* f_b2 = (const float*)d_in[9];
    const float* f_w3 = (const float*)d_in[10];
    const float* f_b3 = (const float*)d_in[11];
    const float* damping = (const float*)d_in[12];
    const float* dt   = (const float*)d_in[13];

    float* force_ws = (float*)d_ws;                 // BB*NN*DD floats
    float* mass_ws  = force_ws + BB * NN * DD;      // BB*NN floats

    mass_kernel<<<(BB * NN + 255) / 256, 256, 0, stream>>>(pos, m_w1, m_b1, m_w2, m_b2,
                                                           mass_ws, force_ws);

    const int tpb = NN / BI;
    const int TP = tpb * (tpb + 1) / 2;
    force_kernel<<<BB * TP, 256, 0, stream>>>(pos, f_w1, f_b1, f_w2, f_b2, f_w3, f_b3,
                                              mass_ws, force_ws);

    integrate_kernel<<<(BB * NN * DD + 255) / 256, 256, 0, stream>>>(
        pos, vel, force_ws, mass_ws, damping, dt, (float*)d_out);
}